// Round 2
// baseline (342.418 us; speedup 1.0000x reference)
//
#include <hip/hip_runtime.h>
#include <hip/hip_bf16.h>
#include <stdint.h>

// LORI_FC: out = blockdiag(x; D) + (x @ Wl^T) @ Wr^T + b_right + bias
// M=8192 tokens, IN=OUT=4096, RANK=64, 64 blocks of 64x64.
// Memory-bound problem (271 MB min traffic -> ~43 us floor). bf16 MFMA compute.
//
// R1 fix: k2_out grid was 4x too large (8192 blocks -> waves with nb up to 255
// wrote out-of-bounds past each output row -> memory fault/abort). Correct
// decomposition: 64 nb x 128 token-groups = 8192 waves = 2048 blocks.

#define M_TOT   8192
#define IN_F    4096
#define OUT_F   4096
#define RANK    64
#define NBLK    64

typedef __attribute__((ext_vector_type(8))) short  bf16x8;
typedef __attribute__((ext_vector_type(4))) float  floatx4;

// ---- ws layout (bytes); total 2637824 (~2.52 MB) ----
#define WS_BIAS   0            // fp32[4096]            : b_right + bias
#define WS_WL     16384        // bf16 [128 kc][64 n][32 k]  : Wl^T B-frag packed
#define WS_BP     540672       // bf16 [64 nb][4 kc][64 n][32 k] : [D;Wr^T] B-frag packed
#define WS_T      1589248      // bf16 [512 mt][2 kc][16 m][32 k] : t A-frag packed

__device__ __forceinline__ unsigned short f2bf(float f) {
    union { float f; unsigned int u; } v; v.f = f;
    unsigned int u = v.u;
    u += 0x7fffu + ((u >> 16) & 1u);   // round-to-nearest-even
    return (unsigned short)(u >> 16);
}

// ---------------- prep: pack weights to bf16 in MFMA fragment order -------------
__global__ __launch_bounds__(256) void prep_kernel(
    const float* __restrict__ diag, const float* __restrict__ Wl,
    const float* __restrict__ Wr,   const float* __restrict__ br,
    const float* __restrict__ bias,
    float* __restrict__ bias_comb, unsigned short* __restrict__ wl_pack,
    unsigned short* __restrict__ bp_pack)
{
    int tid = blockIdx.x * blockDim.x + threadIdx.x;
    int nthr = gridDim.x * blockDim.x;

    for (int i = tid; i < OUT_F; i += nthr)
        bias_comb[i] = br[i] + bias[i];

    // wl_pack[(kc*64 + n)*32 + kk] = Wl[n][kc*32+kk]   (B[k][n] = Wl^T)
    for (int i = tid; i < 128 * 64 * 32; i += nthr) {
        int kk = i & 31; int n = (i >> 5) & 63; int kc = i >> 11;
        wl_pack[i] = f2bf(Wl[n * IN_F + kc * 32 + kk]);
    }

    // bp_pack[((nb*4+kc)*64 + n)*32 + kk]:
    //   k = kc*32+kk; k<64 -> D[nb][k][n]; k>=64 -> Wr[nb*64+n][k-64]
    for (int i = tid; i < 64 * 4 * 64 * 32; i += nthr) {
        int kk = i & 31; int n = (i >> 5) & 63; int kc = (i >> 11) & 3; int nb = i >> 13;
        int k = kc * 32 + kk;
        float v = (k < 64) ? diag[(nb * 64 + k) * 64 + n]
                           : Wr[(size_t)(nb * 64 + n) * RANK + (k - 64)];
        bp_pack[i] = f2bf(v);
    }
}

// ---------------- K1: t = x @ Wl^T  (one wave per 16-token tile) ----------------
__global__ __launch_bounds__(256) void k1_lowrank(
    const float* __restrict__ x, const unsigned short* __restrict__ wl_pack,
    unsigned short* __restrict__ t_pack)
{
    int wave = blockIdx.x * 4 + (threadIdx.x >> 6);   // 0..511 = m-tile index
    int lane = threadIdx.x & 63;
    int q = lane >> 4, l = lane & 15;
    int mt = wave;
    int m0 = mt * 16;

    const float* xrow = x + (size_t)(m0 + l) * IN_F + q * 8;
    floatx4 acc[4] = {};   // 4 n-tiles of 16 ranks

    #pragma unroll 2
    for (int kc = 0; kc < 128; ++kc) {
        const float* ap = xrow + kc * 32;
        float4 a0 = *(const float4*)(ap);
        float4 a1 = *(const float4*)(ap + 4);
        bf16x8 af;
        af[0] = (short)f2bf(a0.x); af[1] = (short)f2bf(a0.y);
        af[2] = (short)f2bf(a0.z); af[3] = (short)f2bf(a0.w);
        af[4] = (short)f2bf(a1.x); af[5] = (short)f2bf(a1.y);
        af[6] = (short)f2bf(a1.z); af[7] = (short)f2bf(a1.w);
        #pragma unroll
        for (int nt = 0; nt < 4; ++nt) {
            bf16x8 bf = *(const bf16x8*)(wl_pack + ((size_t)(kc * 64 + nt * 16 + l) * 32 + q * 8));
            acc[nt] = __builtin_amdgcn_mfma_f32_16x16x32_bf16(af, bf, acc[nt], 0, 0, 0);
        }
    }

    // D layout: m = q*4 + r, n = nt*16 + l. Write t bf16 in A-frag-packed order:
    // t_pack[((mt*2 + n/32)*16 + m)*32 + (n%32)]
    #pragma unroll
    for (int nt = 0; nt < 4; ++nt) {
        int n = nt * 16 + l;
        #pragma unroll
        for (int r = 0; r < 4; ++r) {
            int m = q * 4 + r;
            t_pack[((size_t)(mt * 2 + (n >> 5)) * 16 + m) * 32 + (n & 31)] = f2bf(acc[nt][r]);
        }
    }
}

// ---------------- K2: out_blk = [x_blk | t] @ [D;Wr^T] + bias -------------------
__global__ __launch_bounds__(256) void k2_out(
    const float* __restrict__ x, const unsigned short* __restrict__ bp_pack,
    const unsigned short* __restrict__ t_pack, const float* __restrict__ bias_comb,
    float* __restrict__ out)
{
    int wave = blockIdx.x * 4 + (threadIdx.x >> 6);   // 0..8191
    int lane = threadIdx.x & 63;
    int nb = wave >> 7;        // output block 0..63
    int mg = wave & 127;       // 64-token group 0..127
    int q = lane >> 4, l = lane & 15;

    // B fragments for this block: 4 k-chunks x 4 n-tiles, register-resident (64 VGPRs)
    bf16x8 bfrag[4][4];
    #pragma unroll
    for (int kc = 0; kc < 4; ++kc)
        #pragma unroll
        for (int nt = 0; nt < 4; ++nt)
            bfrag[kc][nt] = *(const bf16x8*)(bp_pack +
                (((size_t)(nb * 4 + kc) * 64 + nt * 16 + l) * 32 + q * 8));

    float bval[4];
    #pragma unroll
    for (int nt = 0; nt < 4; ++nt)
        bval[nt] = bias_comb[nb * 64 + nt * 16 + l];

    for (int sub = 0; sub < 4; ++sub) {
        int mt = mg * 4 + sub;
        int m0 = mt * 16;

        bf16x8 afrag[4];
        const float* xp = x + (size_t)(m0 + l) * IN_F + nb * 64 + q * 8;
        #pragma unroll
        for (int kc = 0; kc < 2; ++kc) {
            float4 a0 = *(const float4*)(xp + kc * 32);
            float4 a1 = *(const float4*)(xp + kc * 32 + 4);
            bf16x8 af;
            af[0] = (short)f2bf(a0.x); af[1] = (short)f2bf(a0.y);
            af[2] = (short)f2bf(a0.z); af[3] = (short)f2bf(a0.w);
            af[4] = (short)f2bf(a1.x); af[5] = (short)f2bf(a1.y);
            af[6] = (short)f2bf(a1.z); af[7] = (short)f2bf(a1.w);
            afrag[kc] = af;
        }
        #pragma unroll
        for (int kc = 0; kc < 2; ++kc)
            afrag[2 + kc] = *(const bf16x8*)(t_pack +
                ((size_t)(mt * 2 + kc) * 16 + l) * 32 + q * 8);

        floatx4 acc[4] = {};
        #pragma unroll
        for (int kc = 0; kc < 4; ++kc)
            #pragma unroll
            for (int nt = 0; nt < 4; ++nt)
                acc[nt] = __builtin_amdgcn_mfma_f32_16x16x32_bf16(afrag[kc], bfrag[kc][nt], acc[nt], 0, 0, 0);

        // D: row m = q*4+r, col n = nt*16+l
        float* op = out + (size_t)m0 * OUT_F + nb * 64;
        #pragma unroll
        for (int nt = 0; nt < 4; ++nt)
            #pragma unroll
            for (int r = 0; r < 4; ++r)
                op[(size_t)(q * 4 + r) * OUT_F + nt * 16 + l] = acc[nt][r] + bval[nt];
    }
}

extern "C" void kernel_launch(void* const* d_in, const int* in_sizes, int n_in,
                              void* d_out, int out_size, void* d_ws, size_t ws_size,
                              hipStream_t stream) {
    const float* x    = (const float*)d_in[0];
    const float* diag = (const float*)d_in[1];
    const float* Wl   = (const float*)d_in[2];
    const float* Wr   = (const float*)d_in[3];
    const float* br   = (const float*)d_in[4];
    const float* bias = (const float*)d_in[5];
    float* out = (float*)d_out;

    char* ws = (char*)d_ws;
    float*          bias_comb = (float*)(ws + WS_BIAS);
    unsigned short* wl_pack   = (unsigned short*)(ws + WS_WL);
    unsigned short* bp_pack   = (unsigned short*)(ws + WS_BP);
    unsigned short* t_pack    = (unsigned short*)(ws + WS_T);

    hipLaunchKernelGGL(prep_kernel, dim3(256), dim3(256), 0, stream,
                       diag, Wl, Wr, br, bias, bias_comb, wl_pack, bp_pack);
    hipLaunchKernelGGL(k1_lowrank, dim3(M_TOT / 16 / 4), dim3(256), 0, stream,
                       x, wl_pack, t_pack);
    // 8192 waves total: 64 output blocks x 128 token-groups (64 tokens each).
    // 4 waves/block -> 2048 blocks. (R0 bug: this was 8192 blocks -> OOB.)
    hipLaunchKernelGGL(k2_out, dim3(2048), dim3(256), 0, stream,
                       x, bp_pack, t_pack, bias_comb, out);
}

// Round 3
// 315.374 us; speedup vs baseline: 1.0858x; 1.0858x over previous
//
#include <hip/hip_runtime.h>
#include <hip/hip_bf16.h>
#include <stdint.h>

// LORI_FC: out = blockdiag(x; D) + (x @ Wl^T) @ Wr^T + b_right + bias
// M=8192 tokens, IN=OUT=4096, RANK=64, 64 blocks of 64x64.
// Traffic floor: x read 2x (K1,K2) + out write = 402 MB ~ 64 us @ 6.3 TB/s.
//
// R2: (a) K1 k-split 8x (512->4096 waves; was 5.4% occupancy, 8.5% HBM,
//     latency-bound at 103 us) with fp32 atomicAdd into zeroed t buffer;
//     (b) prep reads coalesced (was stride-256B gathers);
//     (c) K2 depth-1 software pipeline to keep loads in flight.

#define M_TOT   8192
#define IN_F    4096
#define OUT_F   4096
#define RANK    64
#define NBLK    64

typedef __attribute__((ext_vector_type(8))) short  bf16x8;
typedef __attribute__((ext_vector_type(4))) float  floatx4;

// ---- ws layout (bytes); total ~3.5 MB ----
#define WS_BIAS   0            // fp32[4096]                     : b_right + bias
#define WS_WL     16384        // bf16 [128 kc][64 n][32 k]      : Wl^T B-frag packed
#define WS_BP     540672       // bf16 [64 nb][4 kc][64 n][32 k] : [D;Wr^T] B-frag packed
#define WS_T      1589248      // fp32 [8192 m][64 r]            : t (atomic accum), 2 MB

__device__ __forceinline__ unsigned short f2bf(float f) {
    union { float f; unsigned int u; } v; v.f = f;
    unsigned int u = v.u;
    u += 0x7fffu + ((u >> 16) & 1u);   // round-to-nearest-even
    return (unsigned short)(u >> 16);
}

// ---------------- prep: pack weights to bf16 in MFMA fragment order -------------
// Coalesced READS (linear over each source); scattered 2B writes are
// fire-and-forget and absorbed by L2 write-back (total 2.6 MB).
__global__ __launch_bounds__(256) void prep_kernel(
    const float* __restrict__ diag, const float* __restrict__ Wl,
    const float* __restrict__ Wr,   const float* __restrict__ br,
    const float* __restrict__ bias,
    float* __restrict__ bias_comb, unsigned short* __restrict__ wl_pack,
    unsigned short* __restrict__ bp_pack)
{
    int tid = blockIdx.x * blockDim.x + threadIdx.x;
    int nthr = gridDim.x * blockDim.x;

    for (int i = tid; i < OUT_F; i += nthr)
        bias_comb[i] = br[i] + bias[i];

    // Wl[n][c]  (n=i>>12, c=i&4095) -> wl_pack[((c>>5)*64 + n)*32 + (c&31)]
    for (int i = tid; i < 64 * 4096; i += nthr) {
        int n = i >> 12, c = i & 4095;
        wl_pack[((size_t)(c >> 5) * 64 + n) * 32 + (c & 31)] = f2bf(Wl[i]);
    }

    // diag[nb][k][n] (nb=i>>12, k=(i>>6)&63, n=i&63), concat-k = k (0..63)
    //   -> bp_pack[((nb*4 + (k>>5))*64 + n)*32 + (k&31)]
    for (int i = tid; i < 64 * 64 * 64; i += nthr) {
        int nb = i >> 12, k = (i >> 6) & 63, n = i & 63;
        bp_pack[(((size_t)nb * 4 + (k >> 5)) * 64 + n) * 32 + (k & 31)] = f2bf(diag[i]);
    }

    // Wr[nb*64+n][r] (nb=i>>12, n=(i>>6)&63, r=i&63), concat-k = 64+r
    //   -> bp_pack[((nb*4 + ((64+r)>>5))*64 + n)*32 + ((64+r)&31)]
    for (int i = tid; i < 64 * 64 * 64; i += nthr) {
        int nb = i >> 12, n = (i >> 6) & 63, r = i & 63;
        int kt = 64 + r;
        bp_pack[(((size_t)nb * 4 + (kt >> 5)) * 64 + n) * 32 + (kt & 31)] = f2bf(Wr[i]);
    }
}

// ---------------- K1: t += x @ Wl^T, k-split 8x, fp32 atomic accumulate ---------
// 4096 waves (16/CU). Wave (mt, ks): 16 tokens x 512 features -> rank-64 partial.
__global__ __launch_bounds__(256) void k1_lowrank(
    const float* __restrict__ x, const unsigned short* __restrict__ wl_pack,
    float* __restrict__ t)
{
    int wave = blockIdx.x * 4 + (threadIdx.x >> 6);   // 0..4095
    int lane = threadIdx.x & 63;
    int q = lane >> 4, l = lane & 15;
    int mt = wave >> 3;            // m-tile 0..511
    int ks = wave & 7;             // k-chunk 0..7
    int m0 = mt * 16;
    int kc0 = ks * 16;

    const float* xrow = x + (size_t)(m0 + l) * IN_F + q * 8;
    floatx4 acc[4] = {};   // 4 n-tiles of 16 ranks

    #pragma unroll 4
    for (int kc = kc0; kc < kc0 + 16; ++kc) {
        const float* ap = xrow + kc * 32;
        float4 a0 = *(const float4*)(ap);
        float4 a1 = *(const float4*)(ap + 4);
        bf16x8 af;
        af[0] = (short)f2bf(a0.x); af[1] = (short)f2bf(a0.y);
        af[2] = (short)f2bf(a0.z); af[3] = (short)f2bf(a0.w);
        af[4] = (short)f2bf(a1.x); af[5] = (short)f2bf(a1.y);
        af[6] = (short)f2bf(a1.z); af[7] = (short)f2bf(a1.w);
        #pragma unroll
        for (int nt = 0; nt < 4; ++nt) {
            bf16x8 bf = *(const bf16x8*)(wl_pack + ((size_t)(kc * 64 + nt * 16 + l) * 32 + q * 8));
            acc[nt] = __builtin_amdgcn_mfma_f32_16x16x32_bf16(af, bf, acc[nt], 0, 0, 0);
        }
    }

    // D layout: m = q*4+r, n = nt*16+l. Accumulate into t[m][n] (fp32).
    #pragma unroll
    for (int nt = 0; nt < 4; ++nt)
        #pragma unroll
        for (int r = 0; r < 4; ++r)
            atomicAdd(&t[(size_t)(m0 + q * 4 + r) * RANK + nt * 16 + l], acc[nt][r]);
}

// ---------------- K2: out_blk = [x_blk | t] @ [D;Wr^T] + bias -------------------
// 8192 waves: 64 nb x 128 token-groups of 64. Depth-1 pipelined loads.
__global__ __launch_bounds__(256) void k2_out(
    const float* __restrict__ x, const unsigned short* __restrict__ bp_pack,
    const float* __restrict__ t, const float* __restrict__ bias_comb,
    float* __restrict__ out)
{
    int wave = blockIdx.x * 4 + (threadIdx.x >> 6);   // 0..8191
    int lane = threadIdx.x & 63;
    int nb = wave >> 7;        // output block 0..63
    int mg = wave & 127;       // 64-token group 0..127
    int q = lane >> 4, l = lane & 15;

    // B fragments for this block: 4 k-chunks x 4 n-tiles, register-resident
    bf16x8 bfrag[4][4];
    #pragma unroll
    for (int kc = 0; kc < 4; ++kc)
        #pragma unroll
        for (int nt = 0; nt < 4; ++nt)
            bfrag[kc][nt] = *(const bf16x8*)(bp_pack +
                (((size_t)(nb * 4 + kc) * 64 + nt * 16 + l) * 32 + q * 8));

    float bval[4];
    #pragma unroll
    for (int nt = 0; nt < 4; ++nt)
        bval[nt] = bias_comb[nb * 64 + nt * 16 + l];

    // Per sub-tile loads: x features nb*64 + [0..31]+q*8 window (afrag 0,1),
    // t features [0..31]+q*8 and [32..63]+q*8 (afrag 2,3). 8 x float4.
    float4 xa[8], xn[8];
    auto load_sub = [&](int sub, float4* dst) {
        int m0 = (mg * 4 + sub) * 16;
        const float* xp = x + (size_t)(m0 + l) * IN_F + nb * 64 + q * 8;
        dst[0] = *(const float4*)(xp);
        dst[1] = *(const float4*)(xp + 4);
        dst[2] = *(const float4*)(xp + 32);
        dst[3] = *(const float4*)(xp + 36);
        const float* tp = t + (size_t)(m0 + l) * RANK + q * 8;
        dst[4] = *(const float4*)(tp);
        dst[5] = *(const float4*)(tp + 4);
        dst[6] = *(const float4*)(tp + 32);
        dst[7] = *(const float4*)(tp + 36);
    };

    load_sub(0, xa);
    for (int sub = 0; sub < 4; ++sub) {
        if (sub < 3) load_sub(sub + 1, xn);

        bf16x8 afrag[4];
        #pragma unroll
        for (int kc = 0; kc < 4; ++kc) {
            float4 a0 = xa[kc * 2], a1 = xa[kc * 2 + 1];
            bf16x8 af;
            af[0] = (short)f2bf(a0.x); af[1] = (short)f2bf(a0.y);
            af[2] = (short)f2bf(a0.z); af[3] = (short)f2bf(a0.w);
            af[4] = (short)f2bf(a1.x); af[5] = (short)f2bf(a1.y);
            af[6] = (short)f2bf(a1.z); af[7] = (short)f2bf(a1.w);
            afrag[kc] = af;
        }

        floatx4 acc[4] = {};
        #pragma unroll
        for (int kc = 0; kc < 4; ++kc)
            #pragma unroll
            for (int nt = 0; nt < 4; ++nt)
                acc[nt] = __builtin_amdgcn_mfma_f32_16x16x32_bf16(afrag[kc], bfrag[kc][nt], acc[nt], 0, 0, 0);

        // D: row m = q*4+r, col n = nt*16+l
        int m0 = (mg * 4 + sub) * 16;
        float* op = out + (size_t)m0 * OUT_F + nb * 64;
        #pragma unroll
        for (int nt = 0; nt < 4; ++nt)
            #pragma unroll
            for (int r = 0; r < 4; ++r)
                op[(size_t)(q * 4 + r) * OUT_F + nt * 16 + l] = acc[nt][r] + bval[nt];

        #pragma unroll
        for (int i = 0; i < 8; ++i) xa[i] = xn[i];
    }
}

extern "C" void kernel_launch(void* const* d_in, const int* in_sizes, int n_in,
                              void* d_out, int out_size, void* d_ws, size_t ws_size,
                              hipStream_t stream) {
    const float* x    = (const float*)d_in[0];
    const float* diag = (const float*)d_in[1];
    const float* Wl   = (const float*)d_in[2];
    const float* Wr   = (const float*)d_in[3];
    const float* br   = (const float*)d_in[4];
    const float* bias = (const float*)d_in[5];
    float* out = (float*)d_out;

    char* ws = (char*)d_ws;
    float*          bias_comb = (float*)(ws + WS_BIAS);
    unsigned short* wl_pack   = (unsigned short*)(ws + WS_WL);
    unsigned short* bp_pack   = (unsigned short*)(ws + WS_BP);
    float*          t         = (float*)(ws + WS_T);

    // zero the atomic accumulator (ws is re-poisoned 0xAA before every launch)
    hipMemsetAsync(t, 0, (size_t)M_TOT * RANK * sizeof(float), stream);

    hipLaunchKernelGGL(prep_kernel, dim3(512), dim3(256), 0, stream,
                       diag, Wl, Wr, br, bias, bias_comb, wl_pack, bp_pack);
    // 4096 waves = 512 m-tiles x 8 k-chunks -> 1024 blocks
    hipLaunchKernelGGL(k1_lowrank, dim3(1024), dim3(256), 0, stream,
                       x, wl_pack, t);
    // 8192 waves = 64 nb x 128 token-groups -> 2048 blocks
    hipLaunchKernelGGL(k2_out, dim3(2048), dim3(256), 0, stream,
                       x, bp_pack, t, bias_comb, out);
}

// Round 4
// 308.238 us; speedup vs baseline: 1.1109x; 1.0232x over previous
//
#include <hip/hip_runtime.h>
#include <hip/hip_bf16.h>
#include <stdint.h>

// LORI_FC: out = blockdiag(x; D) + (x @ Wl^T) @ Wr^T + b_right + bias
// M=8192 tokens, IN=OUT=4096, RANK=64, 64 blocks of 64x64.
//
// R3: fuse K1+K2 -> single kernel reading x ONCE (268 MB floor ~43 us).
// Key insight: wave w's feature slice [1024w,1024w+1024) is exactly the x
// input needed by output blocks nb in [16w,16w+16) (block-diagonal structure),
// so x stays register-resident per wave; only t (16x64) crosses waves via LDS.
// Measured R3 baseline: ~140 us of dur_us is harness reset (512 MiB ws poison
// = 80 us fills in top-5); controllable part was ~175 us (k1 ~70 + k2 ~90).

#define M_TOT   8192
#define IN_F    4096
#define OUT_F   4096
#define RANK    64
#define NBLK    64

typedef __attribute__((ext_vector_type(8))) short  bf16x8;
typedef __attribute__((ext_vector_type(4))) float  floatx4;

// ---- ws layout (bytes) ----
#define WS_BIAS   0            // fp32[4096]                     : b_right + bias
#define WS_WL     16384        // bf16 [128 kc][64 n][32 k]      : Wl^T B-frag packed
#define WS_BP     540672       // bf16 [64 nb][4 kc][64 n][32 k] : [D;Wr^T] B-frag packed

#define S_TP 68                // t_part LDS row stride (floats); 272B = 17x16B aligned

__device__ __forceinline__ unsigned short f2bf(float f) {
    union { float f; unsigned int u; } v; v.f = f;
    unsigned int u = v.u;
    u += 0x7fffu + ((u >> 16) & 1u);   // round-to-nearest-even
    return (unsigned short)(u >> 16);
}

__device__ __forceinline__ bf16x8 cvt8(float4 a0, float4 a1) {
    bf16x8 af;
    af[0] = (short)f2bf(a0.x); af[1] = (short)f2bf(a0.y);
    af[2] = (short)f2bf(a0.z); af[3] = (short)f2bf(a0.w);
    af[4] = (short)f2bf(a1.x); af[5] = (short)f2bf(a1.y);
    af[6] = (short)f2bf(a1.z); af[7] = (short)f2bf(a1.w);
    return af;
}

// ---------------- prep: pack weights to bf16 in MFMA fragment order -------------
__global__ __launch_bounds__(256) void prep_kernel(
    const float* __restrict__ diag, const float* __restrict__ Wl,
    const float* __restrict__ Wr,   const float* __restrict__ br,
    const float* __restrict__ bias,
    float* __restrict__ bias_comb, unsigned short* __restrict__ wl_pack,
    unsigned short* __restrict__ bp_pack)
{
    int tid = blockIdx.x * blockDim.x + threadIdx.x;
    int nthr = gridDim.x * blockDim.x;

    for (int i = tid; i < OUT_F; i += nthr)
        bias_comb[i] = br[i] + bias[i];

    // Wl[n][c] -> wl_pack[((c>>5)*64 + n)*32 + (c&31)]
    for (int i = tid; i < 64 * 4096; i += nthr) {
        int n = i >> 12, c = i & 4095;
        wl_pack[((size_t)(c >> 5) * 64 + n) * 32 + (c & 31)] = f2bf(Wl[i]);
    }

    // diag[nb][k][n] -> bp_pack[((nb*4 + (k>>5))*64 + n)*32 + (k&31)]
    for (int i = tid; i < 64 * 64 * 64; i += nthr) {
        int nb = i >> 12, k = (i >> 6) & 63, n = i & 63;
        bp_pack[(((size_t)nb * 4 + (k >> 5)) * 64 + n) * 32 + (k & 31)] = f2bf(diag[i]);
    }

    // Wr[nb*64+n][r], concat-k = 64+r -> bp_pack[...]
    for (int i = tid; i < 64 * 64 * 64; i += nthr) {
        int nb = i >> 12, n = (i >> 6) & 63, r = i & 63;
        int kt = 64 + r;
        bp_pack[(((size_t)nb * 4 + (kt >> 5)) * 64 + n) * 32 + (kt & 31)] = f2bf(Wr[i]);
    }
}

// ---------------- fused: t = x@Wl^T (LDS-reduced), out = [x|t]@[D;Wr^T]+bias ----
// 512 workgroups x 4 waves. wg = 16-token m-tile; wave w owns features
// [1024w, 1024w+1024) and output blocks [16w, 16w+16).
__global__ __launch_bounds__(256, 2) void fused_kernel(
    const float* __restrict__ x, const unsigned short* __restrict__ wl_pack,
    const unsigned short* __restrict__ bp_pack, const float* __restrict__ bias_comb,
    float* __restrict__ out)
{
    __shared__ float t_part[4 * 16 * S_TP];   // [wave][m][rank], padded

    int w = threadIdx.x >> 6;       // wave 0..3
    int lane = threadIdx.x & 63;
    int q = lane >> 4, l = lane & 15;
    int mt = blockIdx.x;            // 0..511
    int m0 = mt * 16;
    int kc_g0 = w * 32;             // this wave's first k-chunk (32 feats each)

    const float* xrow = x + (size_t)(m0 + l) * IN_F + q * 8;

    // ---- Phase A: load x slice into registers (A-frag layout), accumulate t ----
    bf16x8 xfrag[32];               // 16 tokens x 1024 features bf16 = 128 VGPRs
    floatx4 tacc[4] = {};           // t partial: 16 tokens x 64 ranks

    #pragma unroll
    for (int kc = 0; kc < 32; ++kc) {
        int kc_g = kc_g0 + kc;
        const float* ap = xrow + kc_g * 32;
        float4 a0 = *(const float4*)(ap);
        float4 a1 = *(const float4*)(ap + 4);
        bf16x8 af = cvt8(a0, a1);
        xfrag[kc] = af;
        #pragma unroll
        for (int nt = 0; nt < 4; ++nt) {
            bf16x8 bf = *(const bf16x8*)(wl_pack + ((size_t)(kc_g * 64 + nt * 16 + l) * 32 + q * 8));
            tacc[nt] = __builtin_amdgcn_mfma_f32_16x16x32_bf16(af, bf, tacc[nt], 0, 0, 0);
        }
    }

    // write t partial to LDS: C/D layout m=q*4+r, n=nt*16+l  (2-way bank alias max)
    #pragma unroll
    for (int nt = 0; nt < 4; ++nt)
        #pragma unroll
        for (int r = 0; r < 4; ++r)
            t_part[w * 16 * S_TP + (q * 4 + r) * S_TP + nt * 16 + l] = tacc[nt][r];

    __syncthreads();

    // ---- reduce t across waves, build A-frags: t[m=l][k=kc2*32+q*8+j] ----
    bf16x8 tfrag[2];
    #pragma unroll
    for (int kc2 = 0; kc2 < 2; ++kc2) {
        float4 s0 = {0.f, 0.f, 0.f, 0.f}, s1 = {0.f, 0.f, 0.f, 0.f};
        #pragma unroll
        for (int p = 0; p < 4; ++p) {
            const float* tp = &t_part[p * 16 * S_TP + l * S_TP + kc2 * 32 + q * 8];
            float4 v0 = *(const float4*)(tp);
            float4 v1 = *(const float4*)(tp + 4);
            s0.x += v0.x; s0.y += v0.y; s0.z += v0.z; s0.w += v0.w;
            s1.x += v1.x; s1.y += v1.y; s1.z += v1.z; s1.w += v1.w;
        }
        tfrag[kc2] = cvt8(s0, s1);
    }

    // ---- Phase B: 16 output blocks, x frags already in registers ----
    #pragma unroll
    for (int i = 0; i < 16; ++i) {
        int nb = w * 16 + i;

        bf16x8 bfrag[4][4];
        #pragma unroll
        for (int kc = 0; kc < 4; ++kc)
            #pragma unroll
            for (int nt = 0; nt < 4; ++nt)
                bfrag[kc][nt] = *(const bf16x8*)(bp_pack +
                    (((size_t)(nb * 4 + kc) * 64 + nt * 16 + l) * 32 + q * 8));

        floatx4 acc[4];
        #pragma unroll
        for (int nt = 0; nt < 4; ++nt) {
            float bv = bias_comb[nb * 64 + nt * 16 + l];
            acc[nt][0] = bv; acc[nt][1] = bv; acc[nt][2] = bv; acc[nt][3] = bv;
        }

        #pragma unroll
        for (int kc = 0; kc < 4; ++kc) {
            bf16x8 af = (kc < 2) ? xfrag[2 * i + kc] : tfrag[kc - 2];
            #pragma unroll
            for (int nt = 0; nt < 4; ++nt)
                acc[nt] = __builtin_amdgcn_mfma_f32_16x16x32_bf16(af, bfrag[kc][nt], acc[nt], 0, 0, 0);
        }

        float* op = out + (size_t)m0 * OUT_F + nb * 64;
        #pragma unroll
        for (int nt = 0; nt < 4; ++nt)
            #pragma unroll
            for (int r = 0; r < 4; ++r)
                op[(size_t)(q * 4 + r) * OUT_F + nt * 16 + l] = acc[nt][r];
    }
}

extern "C" void kernel_launch(void* const* d_in, const int* in_sizes, int n_in,
                              void* d_out, int out_size, void* d_ws, size_t ws_size,
                              hipStream_t stream) {
    const float* x    = (const float*)d_in[0];
    const float* diag = (const float*)d_in[1];
    const float* Wl   = (const float*)d_in[2];
    const float* Wr   = (const float*)d_in[3];
    const float* br   = (const float*)d_in[4];
    const float* bias = (const float*)d_in[5];
    float* out = (float*)d_out;

    char* ws = (char*)d_ws;
    float*          bias_comb = (float*)(ws + WS_BIAS);
    unsigned short* wl_pack   = (unsigned short*)(ws + WS_WL);
    unsigned short* bp_pack   = (unsigned short*)(ws + WS_BP);

    hipLaunchKernelGGL(prep_kernel, dim3(512), dim3(256), 0, stream,
                       diag, Wl, Wr, br, bias, bias_comb, wl_pack, bp_pack);
    // 512 wg x 4 waves; wave = (16 tokens, 1024-feature slice, 16 output blocks)
    hipLaunchKernelGGL(fused_kernel, dim3(512), dim3(256), 0, stream,
                       x, wl_pack, bp_pack, bias_comb, out);
}